// Round 1
// baseline (437.856 us; speedup 1.0000x reference)
//
#include <hip/hip_runtime.h>

#define B_ 64
#define N_ 196
#define D_ 768
#define H_ 3072
#define M_ (B_*N_)   // 12544

typedef int int4v __attribute__((ext_vector_type(4)));
typedef signed char i8;

// ---- workspace layout ----
// float-indexed
#define WS_MAX 0                 // float[8]: 0 n1w,1 attn,2 g1,3 n2,4 fc1,5 fc2,6 g2
#define WS_W1F 16
#define WS_B1F (16+768)
#define WS_G1F (16+768*2)
#define WS_W2F (16+768*3)
#define WS_B2F (16+768*4)
#define WS_G2F (16+768*5)
#define WS_BA  (16+768*6)        // int[196]
#define WS_BF1 (WS_BA+256)       // int[3072]
#define WS_BF2 (WS_BF1+3072)     // int[768]
// byte offsets
#define OFF_WA   40960ull
#define OFF_FC1  81920ull
#define OFF_FC2  (OFF_FC1+2359296ull)
#define OFF_Q1   (OFF_FC2+2359296ull)
#define OFF_X2   (OFF_Q1+9633792ull)
#define OFF_Q3   (OFF_X2+9633792ull)
#define OFF_Q4   (OFF_Q3+9633792ull)

__device__ __forceinline__ float clamp8(float v){ return fminf(fmaxf(v,-128.f),127.f); }

__global__ void k_init(float* wsmax, const float* __restrict__ act, float* out_tail){
    if (threadIdx.x < 8) wsmax[threadIdx.x] = 0.f;
    if (threadIdx.x == 0) *out_tail = act[7];
}

__global__ void k_maxabs(const float* __restrict__ p0, const float* __restrict__ p1,
                         const float* __restrict__ p2, const float* __restrict__ p3,
                         const float* __restrict__ p4, const float* __restrict__ p5,
                         const float* __restrict__ p6, float* wsmax){
    const float* ps[7] = {p0,p1,p2,p3,p4,p5,p6};
    const int    ns[7] = {768, 38416, 768, 768, 2359296, 2359296, 768};
    int tid = blockIdx.y;
    const float* p = ps[tid]; int n = ns[tid];
    float m = 0.f;
    for (int i = blockIdx.x*blockDim.x + threadIdx.x; i < n; i += gridDim.x*blockDim.x)
        m = fmaxf(m, fabsf(p[i]));
    #pragma unroll
    for (int off = 32; off; off >>= 1) m = fmaxf(m, __shfl_down(m, off, 64));
    __shared__ float red[4];
    int lane = threadIdx.x & 63, wv = threadIdx.x >> 6;
    if (lane == 0) red[wv] = m;
    __syncthreads();
    if (threadIdx.x == 0){
        float mm = red[0];
        for (int w = 1; w < (int)blockDim.x/64; w++) mm = fmaxf(mm, red[w]);
        atomicMax((unsigned*)&wsmax[tid], __float_as_uint(mm));
    }
}

__global__ void k_qweights(const float* __restrict__ n1w, const float* __restrict__ n1b,
                           const float* __restrict__ aw,  const float* __restrict__ ab,
                           const float* __restrict__ g1w, const float* __restrict__ n2w,
                           const float* __restrict__ n2b, const float* __restrict__ f1w,
                           const float* __restrict__ f1b, const float* __restrict__ f2w,
                           const float* __restrict__ f2b, const float* __restrict__ g2w,
                           const float* __restrict__ act, char* ws){
    float* fws = (float*)ws;
    int*   iws = (int*)ws;
    const float* mx = fws + WS_MAX;
    long i = (long)blockIdx.x*blockDim.x + threadIdx.x;
    const long F = 2359296;
    if (i < F){ float sf = mx[4]/127.0f;
        ((i8*)(ws+OFF_FC1))[i] = (i8)(int)fminf(fmaxf(rintf(f1w[i]/sf),-128.f),127.f); return; }
    i -= F;
    if (i < F){ float sf = mx[5]/127.0f;
        ((i8*)(ws+OFF_FC2))[i] = (i8)(int)fminf(fmaxf(rintf(f2w[i]/sf),-128.f),127.f); return; }
    i -= F;
    if (i < 38416){ float sf = mx[1]/127.0f;
        ((i8*)(ws+OFF_WA))[i] = (i8)(int)fminf(fmaxf(rintf(aw[i]/sf),-128.f),127.f); return; }
    i -= 38416;
    if (i < 768){ float sf = mx[0]/127.0f; fws[WS_W1F+i] = rintf(n1w[i]/sf); return; }
    i -= 768;
    if (i < 768){ float sf = mx[0]/127.0f; fws[WS_B1F+i] = rintf(n1b[i]/(act[0]*sf)); return; }
    i -= 768;
    if (i < 768){ float sf = mx[2]/127.0f; fws[WS_G1F+i] = rintf(g1w[i]/sf); return; }
    i -= 768;
    if (i < 768){ float sf = mx[3]/127.0f; fws[WS_W2F+i] = rintf(n2w[i]/sf); return; }
    i -= 768;
    if (i < 768){ float sf = mx[3]/127.0f; fws[WS_B2F+i] = rintf(n2b[i]/(act[3]*sf)); return; }
    i -= 768;
    if (i < 768){ float sf = mx[6]/127.0f; fws[WS_G2F+i] = rintf(g2w[i]/sf); return; }
    i -= 768;
    if (i < 196){ float sf = mx[1]/127.0f; iws[WS_BA+i] = (int)rintf(ab[i]/(act[1]*sf)); return; }
    i -= 196;
    if (i < 3072){ float sf = mx[4]/127.0f; iws[WS_BF1+i] = (int)rintf(f1b[i]/(act[4]*sf)); return; }
    i -= 3072;
    if (i < 768){ float sf = mx[5]/127.0f; iws[WS_BF2+i] = (int)rintf(f2b[i]/(act[5]*sf)); return; }
}

// norm1 + quant_act1 -> q1 int8 [b,n,d]
__global__ __launch_bounds__(256) void k_stage1(const float4* __restrict__ x,
                                                const char* __restrict__ ws,
                                                const float* __restrict__ act,
                                                char4* __restrict__ q1){
    int i = blockIdx.x*256 + threadIdx.x;
    if (i >= B_*N_*D_/4) return;
    const float* fws = (const float*)ws;
    float a0 = act[0];
    float w1sf = fws[WS_MAX+0]/127.0f;
    float r1 = (a0*w1sf)/act[1];
    int d4 = i % (D_/4);
    float4 xv = x[i];
    float4 wv = ((const float4*)(fws+WS_W1F))[d4];
    float4 bv = ((const float4*)(fws+WS_B1F))[d4];
    float o0 = rintf(xv.x/a0*wv.x + bv.x);
    float o1 = rintf(xv.y/a0*wv.y + bv.y);
    float o2 = rintf(xv.z/a0*wv.z + bv.z);
    float o3 = rintf(xv.w/a0*wv.w + bv.w);
    float q0 = clamp8(rintf(o0*r1)), qy = clamp8(rintf(o1*r1));
    float qz = clamp8(rintf(o2*r1)), qw = clamp8(rintf(o3*r1));
    q1[i] = make_char4((i8)(int)q0,(i8)(int)qy,(i8)(int)qz,(i8)(int)qw);
}

// attn GEMM (rank-1 broadcast over tokens) + quant_act2 + gamma1 + residual +
// quant_act_int32_1 + norm2 + quant_act3.  Writes x2 int8, q3 int8 at [b,n,d].
__global__ __launch_bounds__(192) void k_attn(const char* __restrict__ ws,
                                              const float* __restrict__ x,
                                              const float* __restrict__ act){
    const float* fws = (const float*)ws;
    const int*   iws = (const int*)ws;
    const i8* q1 = (const i8*)(ws+OFF_Q1);
    const i8* wa = (const i8*)(ws+OFF_WA);
    i8* x2 = (i8*)(ws+OFF_X2);
    i8* q3 = (i8*)(ws+OFF_Q3);
    int b = blockIdx.x, ob = blockIdx.y*14;
    int t = threadIdx.x;
    __shared__ int4v wasT[196];
    __shared__ int bas[14];
    i8* wt = (i8*)wasT;
    for (int k = t; k < 196; k += 192){
        #pragma unroll
        for (int ot = 0; ot < 14; ot++) wt[k*16+ot] = wa[(size_t)(ob+ot)*196 + k];
        wt[k*16+14] = 0; wt[k*16+15] = 0;
    }
    if (t < 14) bas[t] = iws[WS_BA + ob + t];
    __syncthreads();
    int acc[14][4];
    #pragma unroll
    for (int ot = 0; ot < 14; ot++){ acc[ot][0]=0; acc[ot][1]=0; acc[ot][2]=0; acc[ot][3]=0; }
    const char4* q1b = (const char4*)(q1 + (size_t)b*N_*D_);
    for (int ii = 0; ii < 196; ii++){
        char4 q = q1b[ii*(D_/4) + t];
        union { int4v v; i8 c[16]; } wu;
        wu.v = wasT[ii];
        int q0=q.x, qy=q.y, qz=q.z, qw=q.w;
        #pragma unroll
        for (int ot = 0; ot < 14; ot++){
            int w = wu.c[ot];
            acc[ot][0] += w*q0; acc[ot][1] += w*qy;
            acc[ot][2] += w*qz; acc[ot][3] += w*qw;
        }
    }
    float a0=act[0], a1=act[1], a2=act[2], a3=act[3], a4=act[4];
    float wasf = fws[WS_MAX+1]/127.0f; float r2  = (a1*wasf)/a2;
    float g1sf = fws[WS_MAX+2]/127.0f; float r3a = (a2*g1sf)/a3; float r3b = a0/a3;
    float w2sf = fws[WS_MAX+3]/127.0f; float r4  = (a3*w2sf)/a4;
    float4 g1 = ((const float4*)(fws+WS_G1F))[t];
    float4 w2 = ((const float4*)(fws+WS_W2F))[t];
    float4 b2 = ((const float4*)(fws+WS_B2F))[t];
    for (int ot = 0; ot < 14; ot++){
        int o = ob + ot;
        size_t base = ((size_t)b*N_ + o)*(D_/4) + t;
        float4 idv = ((const float4*)x)[base];
        float xr[4], qr[4];
        #define DOQ(j, XC, GC, WC, BC) { \
            float s2 = (float)(acc[ot][j] + bas[ot]); \
            float q2 = clamp8(rintf(s2*r2)); \
            float o3v = q2*GC; \
            float idi = rintf(XC/a0); \
            float tt = rintf(o3v*r3a) + rintf(idi*r3b); \
            tt = clamp8(tt); \
            float o4 = tt*WC + BC; \
            xr[j] = tt; qr[j] = clamp8(rintf(o4*r4)); }
        DOQ(0, idv.x, g1.x, w2.x, b2.x)
        DOQ(1, idv.y, g1.y, w2.y, b2.y)
        DOQ(2, idv.z, g1.z, w2.z, b2.z)
        DOQ(3, idv.w, g1.w, w2.w, b2.w)
        #undef DOQ
        ((char4*)x2)[base] = make_char4((i8)(int)xr[0],(i8)(int)xr[1],(i8)(int)xr[2],(i8)(int)xr[3]);
        ((char4*)q3)[base] = make_char4((i8)(int)qr[0],(i8)(int)qr[1],(i8)(int)qr[2],(i8)(int)qr[3]);
    }
}

// shared int8 GEMM mainloop: 128x128 tile, BK=64, 4 waves each 64x64 (4x4 of 16x16x64)
__device__ __forceinline__ void gemm_i8_loop(const i8* __restrict__ qa, const i8* __restrict__ wb,
                                             int m0, int n0, int K, int4v acc[4][4],
                                             i8* As, i8* Bs, int t){
    int lane = t & 63;
    int wm = (t>>6)&1, wn = t>>7;
    for (int kb = 0; kb < K; kb += 64){
        __syncthreads();
        #pragma unroll
        for (int e = 0; e < 2; e++){
            int id2 = t + e*256, row = id2>>2, c = id2&3;
            *(int4v*)(As + row*80 + c*16) = *(const int4v*)(qa + (size_t)(m0+row)*K + kb + c*16);
            *(int4v*)(Bs + row*80 + c*16) = *(const int4v*)(wb + (size_t)(n0+row)*K + kb + c*16);
        }
        __syncthreads();
        int4v a[4], bb[4];
        #pragma unroll
        for (int mt = 0; mt < 4; mt++)
            a[mt] = *(const int4v*)(As + (wm*64+mt*16+(lane&15))*80 + (lane>>4)*16);
        #pragma unroll
        for (int nt = 0; nt < 4; nt++)
            bb[nt] = *(const int4v*)(Bs + (wn*64+nt*16+(lane&15))*80 + (lane>>4)*16);
        #pragma unroll
        for (int mt = 0; mt < 4; mt++)
            #pragma unroll
            for (int nt = 0; nt < 4; nt++)
                acc[mt][nt] = __builtin_amdgcn_mfma_i32_16x16x64_i8(a[mt], bb[nt], acc[mt][nt], 0,0,0);
    }
}

// fc1: q3[12544,768] x fc1_int[3072,768]^T -> relu -> quant -> q4 int8 [12544,3072]
__global__ __launch_bounds__(256) void k_fc1(const char* __restrict__ ws, const float* __restrict__ act){
    __shared__ char smem[20480];
    const float* fws = (const float*)ws;
    const int*   iws = (const int*)ws;
    const i8* qa = (const i8*)(ws+OFF_Q3);
    const i8* wb = (const i8*)(ws+OFF_FC1);
    const int* bias = iws + WS_BF1;
    i8* qout = (i8*)(ws+OFF_Q4);
    int m0 = blockIdx.x*128, n0 = blockIdx.y*128;
    int t = threadIdx.x, lane = t & 63;
    int wm = (t>>6)&1, wn = t>>7;
    int4v acc[4][4]; int4v zz = {0,0,0,0};
    #pragma unroll
    for (int mt=0;mt<4;mt++) for (int nt=0;nt<4;nt++) acc[mt][nt] = zz;
    gemm_i8_loop(qa, wb, m0, n0, 768, acc, (i8*)smem, (i8*)smem+10240, t);
    float wsf = fws[WS_MAX+4]/127.0f;
    float r5 = (act[4]*wsf)/act[5];
    int bcol[4];
    #pragma unroll
    for (int nt=0;nt<4;nt++) bcol[nt] = bias[n0 + wn*64 + nt*16 + (lane&15)];
    __syncthreads();
    i8* Cs = (i8*)smem;
    #pragma unroll
    for (int mt=0;mt<4;mt++){
        #pragma unroll
        for (int nt=0;nt<4;nt++){
            int nl = wn*64 + nt*16 + (lane&15);
            #pragma unroll
            for (int r=0;r<4;r++){
                int s = acc[mt][nt][r] + bcol[nt];
                if (s < 0) s = 0;
                float q = clamp8(rintf((float)s * r5));
                int ml = wm*64 + mt*16 + (lane>>4)*4 + r;
                Cs[ml*128 + nl] = (i8)(int)q;
            }
        }
    }
    __syncthreads();
    #pragma unroll
    for (int e=0;e<4;e++){
        int id2 = t + e*256;
        int row = id2>>3, c = id2&7;
        *(int4v*)(qout + (size_t)(m0+row)*3072 + n0 + c*16) = *(const int4v*)(Cs + row*128 + c*16);
    }
}

// fc2: q4[12544,3072] x fc2_int[768,3072]^T -> quant_act2 -> gamma2 -> +identity -> final quant -> fp32 out
__global__ __launch_bounds__(256) void k_fc2(const char* __restrict__ ws, const float* __restrict__ act,
                                             float* __restrict__ out){
    __shared__ char smem[20480];
    const float* fws = (const float*)ws;
    const int*   iws = (const int*)ws;
    const i8* qa = (const i8*)(ws+OFF_Q4);
    const i8* wb = (const i8*)(ws+OFF_FC2);
    const int* bias = iws + WS_BF2;
    const float* g2f = fws + WS_G2F;
    const i8* x2 = (const i8*)(ws+OFF_X2);
    int m0 = blockIdx.x*128, n0 = blockIdx.y*128;
    int t = threadIdx.x, lane = t & 63;
    int wm = (t>>6)&1, wn = t>>7;
    int4v acc[4][4]; int4v zz = {0,0,0,0};
    #pragma unroll
    for (int mt=0;mt<4;mt++) for (int nt=0;nt<4;nt++) acc[mt][nt] = zz;
    gemm_i8_loop(qa, wb, m0, n0, 3072, acc, (i8*)smem, (i8*)smem+10240, t);
    float a3=act[3], a5=act[5], a6=act[6], a7=act[7];
    float wsf  = fws[WS_MAX+5]/127.0f; float r6  = (a5*wsf)/a6;
    float g2sf = fws[WS_MAX+6]/127.0f; float r7a = (a6*g2sf)/a7; float r7b = a3/a7;
    int bcol[4]; float g2v[4];
    #pragma unroll
    for (int nt=0;nt<4;nt++){
        int nc = n0 + wn*64 + nt*16 + (lane&15);
        bcol[nt] = bias[nc]; g2v[nt] = g2f[nc];
    }
    #pragma unroll
    for (int mt=0;mt<4;mt++){
        #pragma unroll
        for (int nt=0;nt<4;nt++){
            int nc = n0 + wn*64 + nt*16 + (lane&15);
            #pragma unroll
            for (int r=0;r<4;r++){
                int ml = wm*64 + mt*16 + (lane>>4)*4 + r;
                size_t gi = (size_t)(m0+ml)*768 + nc;
                int s = acc[mt][nt][r] + bcol[nt];
                float q6 = clamp8(rintf((float)s*r6));
                float o7 = q6*g2v[nt];
                float idi = (float)x2[gi];
                float tt = rintf(o7*r7a) + rintf(idi*r7b);
                tt = clamp8(tt);
                out[gi] = tt*a7;
            }
        }
    }
}

extern "C" void kernel_launch(void* const* d_in, const int* in_sizes, int n_in,
                              void* d_out, int out_size, void* d_ws, size_t ws_size,
                              hipStream_t stream){
    const float* x   = (const float*)d_in[0];
    const float* n1w = (const float*)d_in[1];
    const float* n1b = (const float*)d_in[2];
    const float* aw  = (const float*)d_in[3];
    const float* ab  = (const float*)d_in[4];
    const float* g1w = (const float*)d_in[5];
    const float* n2w = (const float*)d_in[6];
    const float* n2b = (const float*)d_in[7];
    const float* f1w = (const float*)d_in[8];
    const float* f1b = (const float*)d_in[9];
    const float* f2w = (const float*)d_in[10];
    const float* f2b = (const float*)d_in[11];
    const float* g2w = (const float*)d_in[12];
    const float* act = (const float*)d_in[13];
    char* ws = (char*)d_ws;
    float* out = (float*)d_out;

    k_init<<<1,64,0,stream>>>((float*)ws, act, out + (size_t)B_*N_*D_);
    k_maxabs<<<dim3(120,7),256,0,stream>>>(n1w, aw, g1w, n2w, f1w, f2w, g2w, (float*)ws);
    long qwThreads = 2L*2359296 + 38416 + 768L*6 + 196 + 3072 + 768;
    k_qweights<<<(int)((qwThreads+255)/256),256,0,stream>>>(n1w,n1b,aw,ab,g1w,n2w,n2b,
                                                            f1w,f1b,f2w,f2b,g2w,act,ws);
    k_stage1<<<(B_*N_*D_/4+255)/256,256,0,stream>>>((const float4*)x, ws, act,
                                                    (char4*)(ws+OFF_Q1));
    k_attn<<<dim3(B_,14),192,0,stream>>>(ws, x, act);
    k_fc1<<<dim3(98,24),256,0,stream>>>(ws, act);
    k_fc2<<<dim3(98,6),256,0,stream>>>(ws, act, out);
}

// Round 2
// 331.985 us; speedup vs baseline: 1.3189x; 1.3189x over previous
//
#include <hip/hip_runtime.h>

#define B_ 64
#define N_ 196
#define D_ 768
#define H_ 3072
#define M_ (B_*N_)   // 12544
#define NP 256       // padded token count for attn GEMM K / M

typedef int int4v __attribute__((ext_vector_type(4)));
typedef signed char i8;

// ---- workspace layout ----
// float/int-indexed params at base
#define WS_MAX 0                 // float[8]: 0 n1w,1 attn,2 g1,3 n2,4 fc1,5 fc2,6 g2
#define WS_W1F 16
#define WS_B1F (16+768)
#define WS_G1F (16+768*2)
#define WS_W2F (16+768*3)
#define WS_B2F (16+768*4)
#define WS_G2F (16+768*5)
#define WS_BA  (16+768*6)        // int[256] (196 used; tail may be read as garbage, never stored)
#define WS_BF1 (WS_BA+256)       // int[3072]
#define WS_BF2 (WS_BF1+3072)     // int[768]
// byte offsets
#define OFF_WA   40960ull                      // i8[256][256] zero-padded attn weight
#define OFF_FC1  (OFF_WA+65536ull)             // i8[3072][768]
#define OFF_FC2  (OFF_FC1+2359296ull)          // i8[768][3072]
#define OFF_X2   (OFF_FC2+2359296ull)          // i8[12544][768]
#define OFF_Q3   (OFF_X2+9633792ull)           // i8[12544][768]
#define OFF_Q4   (OFF_Q3+9633792ull)           // i8[12544][3072]
// q1T aliases q4: written by stage1, fully consumed by attn BEFORE fc1 writes q4
#define OFF_Q1T  OFF_Q4                        // i8[64][768][256]

__device__ __forceinline__ float clamp8(float v){ return fminf(fmaxf(v,-128.f),127.f); }

__global__ void k_init(char* ws, const float* __restrict__ act, float* out_tail){
    int id = blockIdx.x*256 + threadIdx.x;
    if (blockIdx.x == 0){
        float* f = (float*)ws;
        if (threadIdx.x < 8) f[WS_MAX+threadIdx.x] = 0.f;
        if (threadIdx.x == 8) *out_tail = act[7];
    }
    // zero padded attn weight (65536 B = 4096 int4v)
    if (id < 4096){ int4v z = {0,0,0,0}; ((int4v*)(ws+OFF_WA))[id] = z; }
}

__global__ void k_maxabs(const float* __restrict__ p0, const float* __restrict__ p1,
                         const float* __restrict__ p2, const float* __restrict__ p3,
                         const float* __restrict__ p4, const float* __restrict__ p5,
                         const float* __restrict__ p6, float* wsmax){
    const float* ps[7] = {p0,p1,p2,p3,p4,p5,p6};
    const int    ns[7] = {768, 38416, 768, 768, 2359296, 2359296, 768};
    int tid = blockIdx.y;
    const float* p = ps[tid]; int n = ns[tid];
    float m = 0.f;
    for (int i = blockIdx.x*blockDim.x + threadIdx.x; i < n; i += gridDim.x*blockDim.x)
        m = fmaxf(m, fabsf(p[i]));
    #pragma unroll
    for (int off = 32; off; off >>= 1) m = fmaxf(m, __shfl_down(m, off, 64));
    __shared__ float red[4];
    int lane = threadIdx.x & 63, wv = threadIdx.x >> 6;
    if (lane == 0) red[wv] = m;
    __syncthreads();
    if (threadIdx.x == 0){
        float mm = red[0];
        for (int w = 1; w < (int)blockDim.x/64; w++) mm = fmaxf(mm, red[w]);
        atomicMax((unsigned*)&wsmax[tid], __float_as_uint(mm));
    }
}

__global__ void k_qweights(const float* __restrict__ n1w, const float* __restrict__ n1b,
                           const float* __restrict__ aw,  const float* __restrict__ ab,
                           const float* __restrict__ g1w, const float* __restrict__ n2w,
                           const float* __restrict__ n2b, const float* __restrict__ f1w,
                           const float* __restrict__ f1b, const float* __restrict__ f2w,
                           const float* __restrict__ f2b, const float* __restrict__ g2w,
                           const float* __restrict__ act, char* ws){
    float* fws = (float*)ws;
    int*   iws = (int*)ws;
    const float* mx = fws + WS_MAX;
    long i = (long)blockIdx.x*blockDim.x + threadIdx.x;
    const long F = 2359296;
    if (i < F){ float sf = mx[4]/127.0f;
        ((i8*)(ws+OFF_FC1))[i] = (i8)(int)fminf(fmaxf(rintf(f1w[i]/sf),-128.f),127.f); return; }
    i -= F;
    if (i < F){ float sf = mx[5]/127.0f;
        ((i8*)(ws+OFF_FC2))[i] = (i8)(int)fminf(fmaxf(rintf(f2w[i]/sf),-128.f),127.f); return; }
    i -= F;
    if (i < 38416){ float sf = mx[1]/127.0f;
        int o = (int)(i/196), k = (int)(i%196);
        ((i8*)(ws+OFF_WA))[o*NP+k] = (i8)(int)fminf(fmaxf(rintf(aw[i]/sf),-128.f),127.f); return; }
    i -= 38416;
    if (i < 768){ float sf = mx[0]/127.0f; fws[WS_W1F+i] = rintf(n1w[i]/sf); return; }
    i -= 768;
    if (i < 768){ float sf = mx[0]/127.0f; fws[WS_B1F+i] = rintf(n1b[i]/(act[0]*sf)); return; }
    i -= 768;
    if (i < 768){ float sf = mx[2]/127.0f; fws[WS_G1F+i] = rintf(g1w[i]/sf); return; }
    i -= 768;
    if (i < 768){ float sf = mx[3]/127.0f; fws[WS_W2F+i] = rintf(n2w[i]/sf); return; }
    i -= 768;
    if (i < 768){ float sf = mx[3]/127.0f; fws[WS_B2F+i] = rintf(n2b[i]/(act[3]*sf)); return; }
    i -= 768;
    if (i < 768){ float sf = mx[6]/127.0f; fws[WS_G2F+i] = rintf(g2w[i]/sf); return; }
    i -= 768;
    if (i < 196){ float sf = mx[1]/127.0f; iws[WS_BA+i] = (int)rintf(ab[i]/(act[1]*sf)); return; }
    i -= 196;
    if (i < 3072){ float sf = mx[4]/127.0f; iws[WS_BF1+i] = (int)rintf(f1b[i]/(act[4]*sf)); return; }
    i -= 3072;
    if (i < 768){ float sf = mx[5]/127.0f; iws[WS_BF2+i] = (int)rintf(f2b[i]/(act[5]*sf)); return; }
}

// norm1 + quant_act1 -> q1T int8 [b][d][n] (n padded to 256 with zeros), via LDS transpose.
// grid: (12 d-tiles of 64, 4 n-tiles of 64, 64 batches), 256 threads.
__global__ __launch_bounds__(256) void k_stage1(const float* __restrict__ x,
                                                const char* __restrict__ wsc,
                                                char* __restrict__ ws,
                                                const float* __restrict__ act){
    __shared__ i8 T[64][68];
    const float* fws = (const float*)wsc;
    int b = blockIdx.z, n0 = blockIdx.y*64, d0 = blockIdx.x*64;
    int t = threadIdx.x;
    float a0 = act[0];
    float w1sf = fws[WS_MAX+0]/127.0f;
    float r1 = (a0*w1sf)/act[1];
    int dl = (t & 15) * 4;            // local d (4 per thread)
    int d  = d0 + dl;
    float4 wv = *(const float4*)(fws + WS_W1F + d);
    float4 bv = *(const float4*)(fws + WS_B1F + d);
    #pragma unroll
    for (int pass = 0; pass < 4; pass++){
        int nl = (t >> 4) + pass*16;
        int n  = n0 + nl;
        i8 q[4] = {0,0,0,0};
        if (n < 196){
            float4 xv = *(const float4*)(x + ((size_t)b*196 + n)*768 + d);
            float o0 = rintf(xv.x/a0*wv.x + bv.x);
            float o1 = rintf(xv.y/a0*wv.y + bv.y);
            float o2 = rintf(xv.z/a0*wv.z + bv.z);
            float o3 = rintf(xv.w/a0*wv.w + bv.w);
            q[0] = (i8)(int)clamp8(rintf(o0*r1));
            q[1] = (i8)(int)clamp8(rintf(o1*r1));
            q[2] = (i8)(int)clamp8(rintf(o2*r1));
            q[3] = (i8)(int)clamp8(rintf(o3*r1));
        }
        T[dl+0][nl] = q[0]; T[dl+1][nl] = q[1];
        T[dl+2][nl] = q[2]; T[dl+3][nl] = q[3];
    }
    __syncthreads();
    i8* q1T = (i8*)(ws + OFF_Q1T) + (size_t)b*768*NP;
    #pragma unroll
    for (int e = 0; e < 4; e++){
        int id = t + e*256;
        int row = id >> 4, c = (id & 15) * 4;
        int v = *(const int*)&T[row][c];
        *(int*)(q1T + (size_t)(d0+row)*NP + n0 + c) = v;
    }
}

// shared int8 GEMM mainloop: 128x128 tile, BK=64, 4 waves each 64x64 (4x4 of 16x16x64)
__device__ __forceinline__ void gemm_i8_loop(const i8* __restrict__ qa, const i8* __restrict__ wb,
                                             size_t lda, size_t ldb,
                                             int m0, int n0, int K, int4v acc[4][4],
                                             i8* As, i8* Bs, int t){
    int lane = t & 63;
    int wm = (t>>6)&1, wn = t>>7;
    for (int kb = 0; kb < K; kb += 64){
        __syncthreads();
        #pragma unroll
        for (int e = 0; e < 2; e++){
            int id2 = t + e*256, row = id2>>2, c = id2&3;
            *(int4v*)(As + row*80 + c*16) = *(const int4v*)(qa + (size_t)(m0+row)*lda + kb + c*16);
            *(int4v*)(Bs + row*80 + c*16) = *(const int4v*)(wb + (size_t)(n0+row)*ldb + kb + c*16);
        }
        __syncthreads();
        int4v a[4], bb[4];
        #pragma unroll
        for (int mt = 0; mt < 4; mt++)
            a[mt] = *(const int4v*)(As + (wm*64+mt*16+(lane&15))*80 + (lane>>4)*16);
        #pragma unroll
        for (int nt = 0; nt < 4; nt++)
            bb[nt] = *(const int4v*)(Bs + (wn*64+nt*16+(lane&15))*80 + (lane>>4)*16);
        #pragma unroll
        for (int mt = 0; mt < 4; mt++)
            #pragma unroll
            for (int nt = 0; nt < 4; nt++)
                acc[mt][nt] = __builtin_amdgcn_mfma_i32_16x16x64_i8(a[mt], bb[nt], acc[mt][nt], 0,0,0);
    }
}

// attn as int8 MFMA GEMM: C[b][o][d] = sum_k wa_pad[o][k] * q1T[b][d][k]
// + quant_act2 + gamma1 + residual + quant_act_int32_1 + norm2 + quant_act3
// grid: (2 M-tiles, 6 N-tiles, 64 batches), 256 threads.
__global__ __launch_bounds__(256) void k_attn(const char* __restrict__ ws,
                                              const float* __restrict__ x,
                                              const float* __restrict__ act){
    __shared__ char smem[32768];
    const float* fws = (const float*)ws;
    const int*   iws = (const int*)ws;
    const i8* A  = (const i8*)(ws + OFF_WA);
    const i8* Bq = (const i8*)(ws + OFF_Q1T) + (size_t)blockIdx.z*768*NP;
    i8* x2 = (i8*)(ws + OFF_X2);
    i8* q3 = (i8*)(ws + OFF_Q3);
    int b = blockIdx.z;
    int m0 = blockIdx.x*128, n0 = blockIdx.y*128;
    int t = threadIdx.x, lane = t & 63;
    int wm = (t>>6)&1, wn = t>>7;
    int4v acc[4][4]; int4v zz = {0,0,0,0};
    #pragma unroll
    for (int mt=0;mt<4;mt++) for (int nt=0;nt<4;nt++) acc[mt][nt] = zz;
    gemm_i8_loop(A, Bq, NP, NP, m0, n0, NP, acc, (i8*)smem, (i8*)smem+10240, t);

    float a0=act[0], a1=act[1], a2=act[2], a3=act[3], a4=act[4];
    float wasf = fws[WS_MAX+1]/127.0f; float r2  = (a1*wasf)/a2;
    float g1sf = fws[WS_MAX+2]/127.0f; float r3a = (a2*g1sf)/a3; float r3b = a0/a3;
    float w2sf = fws[WS_MAX+3]/127.0f; float r4  = (a3*w2sf)/a4;
    float g1v[4], w2v[4], b2v[4];
    #pragma unroll
    for (int nt=0;nt<4;nt++){
        int d = n0 + wn*64 + nt*16 + (lane&15);
        g1v[nt] = fws[WS_G1F + d]; w2v[nt] = fws[WS_W2F + d]; b2v[nt] = fws[WS_B2F + d];
    }
    __syncthreads();            // GEMM LDS reads done; reuse smem as output repack
    i8* Xs = (i8*)smem;         // [128][128]
    i8* Qs = (i8*)smem + 16384; // [128][128]
    #pragma unroll
    for (int mt=0;mt<4;mt++){
        #pragma unroll
        for (int r=0;r<4;r++){
            int ml = wm*64 + mt*16 + (lane>>4)*4 + r;
            int o  = m0 + ml;
            int ba = iws[WS_BA + o];
            #pragma unroll
            for (int nt=0;nt<4;nt++){
                int nl = wn*64 + nt*16 + (lane&15);
                int d  = n0 + nl;
                float s2 = (float)(acc[mt][nt][r] + ba);
                float q2 = clamp8(rintf(s2*r2));
                float o3v = q2*g1v[nt];
                float xv = (o < 196) ? x[((size_t)b*196 + o)*768 + d] : 0.f;
                float idi = rintf(xv/a0);
                float tt = rintf(o3v*r3a) + rintf(idi*r3b);
                tt = clamp8(tt);
                float o4 = tt*w2v[nt] + b2v[nt];
                float qr = clamp8(rintf(o4*r4));
                Xs[ml*128 + nl] = (i8)(int)tt;
                Qs[ml*128 + nl] = (i8)(int)qr;
            }
        }
    }
    __syncthreads();
    #pragma unroll
    for (int e=0;e<4;e++){
        int id = t + e*256;
        int row = id>>3, c = id&7;
        int o = m0 + row;
        if (o < 196){
            size_t g = ((size_t)b*196 + o)*768 + n0 + c*16;
            *(int4v*)(x2 + g) = *(const int4v*)(Xs + row*128 + c*16);
            *(int4v*)(q3 + g) = *(const int4v*)(Qs + row*128 + c*16);
        }
    }
}

// fc1: q3[12544,768] x fc1_int[3072,768]^T -> relu -> quant -> q4 int8 [12544,3072]
__global__ __launch_bounds__(256) void k_fc1(const char* __restrict__ ws, const float* __restrict__ act){
    __shared__ char smem[20480];
    const float* fws = (const float*)ws;
    const int*   iws = (const int*)ws;
    const i8* qa = (const i8*)(ws+OFF_Q3);
    const i8* wb = (const i8*)(ws+OFF_FC1);
    const int* bias = iws + WS_BF1;
    i8* qout = (i8*)(ws+OFF_Q4);
    int m0 = blockIdx.x*128, n0 = blockIdx.y*128;
    int t = threadIdx.x, lane = t & 63;
    int wm = (t>>6)&1, wn = t>>7;
    int4v acc[4][4]; int4v zz = {0,0,0,0};
    #pragma unroll
    for (int mt=0;mt<4;mt++) for (int nt=0;nt<4;nt++) acc[mt][nt] = zz;
    gemm_i8_loop(qa, wb, 768, 768, m0, n0, 768, acc, (i8*)smem, (i8*)smem+10240, t);
    float wsf = fws[WS_MAX+4]/127.0f;
    float r5 = (act[4]*wsf)/act[5];
    int bcol[4];
    #pragma unroll
    for (int nt=0;nt<4;nt++) bcol[nt] = bias[n0 + wn*64 + nt*16 + (lane&15)];
    __syncthreads();
    i8* Cs = (i8*)smem;
    #pragma unroll
    for (int mt=0;mt<4;mt++){
        #pragma unroll
        for (int nt=0;nt<4;nt++){
            int nl = wn*64 + nt*16 + (lane&15);
            #pragma unroll
            for (int r=0;r<4;r++){
                int s = acc[mt][nt][r] + bcol[nt];
                if (s < 0) s = 0;
                float q = clamp8(rintf((float)s * r5));
                int ml = wm*64 + mt*16 + (lane>>4)*4 + r;
                Cs[ml*128 + nl] = (i8)(int)q;
            }
        }
    }
    __syncthreads();
    #pragma unroll
    for (int e=0;e<4;e++){
        int id2 = t + e*256;
        int row = id2>>3, c = id2&7;
        *(int4v*)(qout + (size_t)(m0+row)*3072 + n0 + c*16) = *(const int4v*)(Cs + row*128 + c*16);
    }
}

// fc2: q4[12544,3072] x fc2_int[768,3072]^T -> quant_act2 -> gamma2 -> +identity -> final quant -> fp32 out
__global__ __launch_bounds__(256) void k_fc2(const char* __restrict__ ws, const float* __restrict__ act,
                                             float* __restrict__ out){
    __shared__ char smem[20480];
    const float* fws = (const float*)ws;
    const int*   iws = (const int*)ws;
    const i8* qa = (const i8*)(ws+OFF_Q4);
    const i8* wb = (const i8*)(ws+OFF_FC2);
    const int* bias = iws + WS_BF2;
    const float* g2f = fws + WS_G2F;
    const i8* x2 = (const i8*)(ws+OFF_X2);
    int m0 = blockIdx.x*128, n0 = blockIdx.y*128;
    int t = threadIdx.x, lane = t & 63;
    int wm = (t>>6)&1, wn = t>>7;
    int4v acc[4][4]; int4v zz = {0,0,0,0};
    #pragma unroll
    for (int mt=0;mt<4;mt++) for (int nt=0;nt<4;nt++) acc[mt][nt] = zz;
    gemm_i8_loop(qa, wb, 3072, 3072, m0, n0, 3072, acc, (i8*)smem, (i8*)smem+10240, t);
    float a3=act[3], a5=act[5], a6=act[6], a7=act[7];
    float wsf  = fws[WS_MAX+5]/127.0f; float r6  = (a5*wsf)/a6;
    float g2sf = fws[WS_MAX+6]/127.0f; float r7a = (a6*g2sf)/a7; float r7b = a3/a7;
    int bcol[4]; float g2v[4];
    #pragma unroll
    for (int nt=0;nt<4;nt++){
        int nc = n0 + wn*64 + nt*16 + (lane&15);
        bcol[nt] = bias[nc]; g2v[nt] = g2f[nc];
    }
    #pragma unroll
    for (int mt=0;mt<4;mt++){
        #pragma unroll
        for (int nt=0;nt<4;nt++){
            int nc = n0 + wn*64 + nt*16 + (lane&15);
            #pragma unroll
            for (int r=0;r<4;r++){
                int ml = wm*64 + mt*16 + (lane>>4)*4 + r;
                size_t gi = (size_t)(m0+ml)*768 + nc;
                int s = acc[mt][nt][r] + bcol[nt];
                float q6 = clamp8(rintf((float)s*r6));
                float o7 = q6*g2v[nt];
                float idi = (float)x2[gi];
                float tt = rintf(o7*r7a) + rintf(idi*r7b);
                tt = clamp8(tt);
                out[gi] = tt*a7;
            }
        }
    }
}

extern "C" void kernel_launch(void* const* d_in, const int* in_sizes, int n_in,
                              void* d_out, int out_size, void* d_ws, size_t ws_size,
                              hipStream_t stream){
    const float* x   = (const float*)d_in[0];
    const float* n1w = (const float*)d_in[1];
    const float* n1b = (const float*)d_in[2];
    const float* aw  = (const float*)d_in[3];
    const float* ab  = (const float*)d_in[4];
    const float* g1w = (const float*)d_in[5];
    const float* n2w = (const float*)d_in[6];
    const float* n2b = (const float*)d_in[7];
    const float* f1w = (const float*)d_in[8];
    const float* f1b = (const float*)d_in[9];
    const float* f2w = (const float*)d_in[10];
    const float* f2b = (const float*)d_in[11];
    const float* g2w = (const float*)d_in[12];
    const float* act = (const float*)d_in[13];
    char* ws = (char*)d_ws;
    float* out = (float*)d_out;

    k_init<<<16,256,0,stream>>>(ws, act, out + (size_t)B_*N_*D_);
    k_maxabs<<<dim3(120,7),256,0,stream>>>(n1w, aw, g1w, n2w, f1w, f2w, g2w, (float*)ws);
    long qwThreads = 2L*2359296 + 38416 + 768L*6 + 196 + 3072 + 768;
    k_qweights<<<(int)((qwThreads+255)/256),256,0,stream>>>(n1w,n1b,aw,ab,g1w,n2w,n2b,
                                                            f1w,f1b,f2w,f2b,g2w,act,ws);
    k_stage1<<<dim3(12,4,64),256,0,stream>>>(x, ws, ws, act);
    k_attn<<<dim3(2,6,64),256,0,stream>>>(ws, x, act);
    k_fc1<<<dim3(98,24),256,0,stream>>>(ws, act);
    k_fc2<<<dim3(98,6),256,0,stream>>>(ws, act, out);
}

// Round 3
// 303.501 us; speedup vs baseline: 1.4427x; 1.0939x over previous
//
#include <hip/hip_runtime.h>

#define B_ 64
#define N_ 196
#define D_ 768
#define H_ 3072
#define M_ (B_*N_)   // 12544
#define NP 256       // padded token count for attn GEMM K / M

typedef int int4v __attribute__((ext_vector_type(4)));
typedef signed char i8;

// ---- workspace layout ----
#define WS_MAX 0                 // float[8]: 0 n1w,1 attn,2 g1,3 n2,4 fc1,5 fc2,6 g2
#define WS_W1F 16
#define WS_B1F (16+768)
#define WS_G1F (16+768*2)
#define WS_W2F (16+768*3)
#define WS_B2F (16+768*4)
#define WS_G2F (16+768*5)
#define WS_BA  (16+768*6)        // int[256]
#define WS_BF1 (WS_BA+256)       // int[3072]
#define WS_BF2 (WS_BF1+3072)     // int[768]
// byte offsets
#define OFF_WA   40960ull                      // i8[256][256] zero-padded attn weight
#define OFF_FC1  (OFF_WA+65536ull)             // i8[3072][768]
#define OFF_FC2  (OFF_FC1+2359296ull)          // i8[768][3072]
#define OFF_X2   (OFF_FC2+2359296ull)          // i8[12544][768]
#define OFF_Q3   (OFF_X2+9633792ull)           // i8[12544][768]
#define OFF_Q4   (OFF_Q3+9633792ull)           // i8[12544][3072]
#define OFF_Q1T  OFF_Q4                        // i8[64][768][256] (aliases q4; disjoint lifetime)

__device__ __forceinline__ float clamp8(float v){ return fminf(fmaxf(v,-128.f),127.f); }

// async global->LDS, 16B per lane. lds dest = wave-uniform base + lane*16
// (our lane->lds mapping is exactly lane*16 within each 1KB chunk).
__device__ __forceinline__ void async16(const void* g, void* l){
    __builtin_amdgcn_global_load_lds((const __attribute__((address_space(1))) void*)g,
                                     (__attribute__((address_space(3))) void*)l, 16, 0, 0);
}

__global__ void k_init(char* ws, const float* __restrict__ act, float* out_tail){
    int id = blockIdx.x*256 + threadIdx.x;
    if (blockIdx.x == 0){
        float* f = (float*)ws;
        if (threadIdx.x < 8) f[WS_MAX+threadIdx.x] = 0.f;
        if (threadIdx.x == 8) *out_tail = act[7];
    }
    if (id < 4096){ int4v z = {0,0,0,0}; ((int4v*)(ws+OFF_WA))[id] = z; }
}

__global__ void k_maxabs(const float* __restrict__ p0, const float* __restrict__ p1,
                         const float* __restrict__ p2, const float* __restrict__ p3,
                         const float* __restrict__ p4, const float* __restrict__ p5,
                         const float* __restrict__ p6, float* wsmax){
    const float* ps[7] = {p0,p1,p2,p3,p4,p5,p6};
    const int    n4s[7] = {192, 9604, 192, 192, 589824, 589824, 192};
    int tid = blockIdx.y;
    const float4* p = (const float4*)ps[tid]; int n4 = n4s[tid];
    float m = 0.f;
    for (int i = blockIdx.x*blockDim.x + threadIdx.x; i < n4; i += gridDim.x*blockDim.x){
        float4 v = p[i];
        m = fmaxf(m, fmaxf(fmaxf(fabsf(v.x),fabsf(v.y)), fmaxf(fabsf(v.z),fabsf(v.w))));
    }
    #pragma unroll
    for (int off = 32; off; off >>= 1) m = fmaxf(m, __shfl_down(m, off, 64));
    __shared__ float red[4];
    int lane = threadIdx.x & 63, wv = threadIdx.x >> 6;
    if (lane == 0) red[wv] = m;
    __syncthreads();
    if (threadIdx.x == 0){
        float mm = red[0];
        for (int w = 1; w < (int)blockDim.x/64; w++) mm = fmaxf(mm, red[w]);
        atomicMax((unsigned*)&wsmax[tid], __float_as_uint(mm));
    }
}

__global__ void k_qweights(const float* __restrict__ n1w, const float* __restrict__ n1b,
                           const float* __restrict__ aw,  const float* __restrict__ ab,
                           const float* __restrict__ g1w, const float* __restrict__ n2w,
                           const float* __restrict__ n2b, const float* __restrict__ f1w,
                           const float* __restrict__ f1b, const float* __restrict__ f2w,
                           const float* __restrict__ f2b, const float* __restrict__ g2w,
                           const float* __restrict__ act, char* ws){
    float* fws = (float*)ws;
    int*   iws = (int*)ws;
    const float* mx = fws + WS_MAX;
    long i = (long)blockIdx.x*blockDim.x + threadIdx.x;
    const long F4 = 589824;
    if (i < F4){ float sf = mx[4]/127.0f;
        float4 v = ((const float4*)f1w)[i];
        char4 o = make_char4(
            (i8)(int)fminf(fmaxf(rintf(v.x/sf),-128.f),127.f),
            (i8)(int)fminf(fmaxf(rintf(v.y/sf),-128.f),127.f),
            (i8)(int)fminf(fmaxf(rintf(v.z/sf),-128.f),127.f),
            (i8)(int)fminf(fmaxf(rintf(v.w/sf),-128.f),127.f));
        ((char4*)(ws+OFF_FC1))[i] = o; return; }
    i -= F4;
    if (i < F4){ float sf = mx[5]/127.0f;
        float4 v = ((const float4*)f2w)[i];
        char4 o = make_char4(
            (i8)(int)fminf(fmaxf(rintf(v.x/sf),-128.f),127.f),
            (i8)(int)fminf(fmaxf(rintf(v.y/sf),-128.f),127.f),
            (i8)(int)fminf(fmaxf(rintf(v.z/sf),-128.f),127.f),
            (i8)(int)fminf(fmaxf(rintf(v.w/sf),-128.f),127.f));
        ((char4*)(ws+OFF_FC2))[i] = o; return; }
    i -= F4;
    if (i < 38416){ float sf = mx[1]/127.0f;
        int o = (int)(i/196), k = (int)(i%196);
        ((i8*)(ws+OFF_WA))[o*NP+k] = (i8)(int)fminf(fmaxf(rintf(aw[i]/sf),-128.f),127.f); return; }
    i -= 38416;
    if (i < 768){ float sf = mx[0]/127.0f; fws[WS_W1F+i] = rintf(n1w[i]/sf); return; }
    i -= 768;
    if (i < 768){ float sf = mx[0]/127.0f; fws[WS_B1F+i] = rintf(n1b[i]/(act[0]*sf)); return; }
    i -= 768;
    if (i < 768){ float sf = mx[2]/127.0f; fws[WS_G1F+i] = rintf(g1w[i]/sf); return; }
    i -= 768;
    if (i < 768){ float sf = mx[3]/127.0f; fws[WS_W2F+i] = rintf(n2w[i]/sf); return; }
    i -= 768;
    if (i < 768){ float sf = mx[3]/127.0f; fws[WS_B2F+i] = rintf(n2b[i]/(act[3]*sf)); return; }
    i -= 768;
    if (i < 768){ float sf = mx[6]/127.0f; fws[WS_G2F+i] = rintf(g2w[i]/sf); return; }
    i -= 768;
    if (i < 196){ float sf = mx[1]/127.0f; iws[WS_BA+i] = (int)rintf(ab[i]/(act[1]*sf)); return; }
    i -= 196;
    if (i < 3072){ float sf = mx[4]/127.0f; iws[WS_BF1+i] = (int)rintf(f1b[i]/(act[4]*sf)); return; }
    i -= 3072;
    if (i < 768){ float sf = mx[5]/127.0f; iws[WS_BF2+i] = (int)rintf(f2b[i]/(act[5]*sf)); return; }
}

// norm1 + quant_act1 -> q1T int8 [b][d][n] (n padded to 256), via LDS transpose.
__global__ __launch_bounds__(256) void k_stage1(const float* __restrict__ x,
                                                const char* __restrict__ wsc,
                                                char* __restrict__ ws,
                                                const float* __restrict__ act){
    __shared__ i8 T[64][68];
    const float* fws = (const float*)wsc;
    int b = blockIdx.z, n0 = blockIdx.y*64, d0 = blockIdx.x*64;
    int t = threadIdx.x;
    float a0 = act[0];
    float w1sf = fws[WS_MAX+0]/127.0f;
    float r1 = (a0*w1sf)/act[1];
    int dl = (t & 15) * 4;
    int d  = d0 + dl;
    float4 wv = *(const float4*)(fws + WS_W1F + d);
    float4 bv = *(const float4*)(fws + WS_B1F + d);
    #pragma unroll
    for (int pass = 0; pass < 4; pass++){
        int nl = (t >> 4) + pass*16;
        int n  = n0 + nl;
        i8 q[4] = {0,0,0,0};
        if (n < 196){
            float4 xv = *(const float4*)(x + ((size_t)b*196 + n)*768 + d);
            float o0 = rintf(xv.x/a0*wv.x + bv.x);
            float o1 = rintf(xv.y/a0*wv.y + bv.y);
            float o2 = rintf(xv.z/a0*wv.z + bv.z);
            float o3 = rintf(xv.w/a0*wv.w + bv.w);
            q[0] = (i8)(int)clamp8(rintf(o0*r1));
            q[1] = (i8)(int)clamp8(rintf(o1*r1));
            q[2] = (i8)(int)clamp8(rintf(o2*r1));
            q[3] = (i8)(int)clamp8(rintf(o3*r1));
        }
        T[dl+0][nl] = q[0]; T[dl+1][nl] = q[1];
        T[dl+2][nl] = q[2]; T[dl+3][nl] = q[3];
    }
    __syncthreads();
    i8* q1T = (i8*)(ws + OFF_Q1T) + (size_t)b*768*NP;
    #pragma unroll
    for (int e = 0; e < 4; e++){
        int id = t + e*256;
        int row = id >> 4, c = (id & 15) * 4;
        int v = *(const int*)&T[row][c];
        *(int*)(q1T + (size_t)(d0+row)*NP + n0 + c) = v;
    }
}

// m97-style int8 GEMM mainloop: 128x128 tile, BK=64, async global->LDS staging,
// unpadded 64B rows, 4 waves each 64x64 (4x4 of 16x16x64).
__device__ __forceinline__ void gemm_i8_loop(const i8* __restrict__ qa, const i8* __restrict__ wb,
                                             size_t lda, size_t ldb,
                                             int m0, int n0, int K, int4v acc[4][4],
                                             i8* As, i8* Bs, int t){
    int lane = t & 63;
    int w = t >> 6;
    int wm = w & 1, wn = w >> 1;
    int lr = lane >> 2, lc = lane & 3;          // 16 rows x 4 chunks per wave-instr
    const i8* ga = qa + (size_t)(m0 + w*32 + lr)*lda + lc*16;
    const i8* gb = wb + (size_t)(n0 + w*32 + lr)*ldb + lc*16;
    i8* lA = As + (w*32 + lr)*64 + lc*16;       // == wave base + lane*16
    i8* lB = Bs + (w*32 + lr)*64 + lc*16;
    for (int kb = 0; kb < K; kb += 64){
        __syncthreads();                         // prev iter's ds_reads done
        async16(ga + kb,            lA);
        async16(ga + kb + 16*lda,   lA + 16*64);
        async16(gb + kb,            lB);
        async16(gb + kb + 16*ldb,   lB + 16*64);
        __syncthreads();                         // drains vmcnt -> LDS valid
        int4v a[4], bb[4];
        #pragma unroll
        for (int mt = 0; mt < 4; mt++)
            a[mt] = *(const int4v*)(As + (wm*64+mt*16+(lane&15))*64 + (lane>>4)*16);
        #pragma unroll
        for (int nt = 0; nt < 4; nt++)
            bb[nt] = *(const int4v*)(Bs + (wn*64+nt*16+(lane&15))*64 + (lane>>4)*16);
        #pragma unroll
        for (int mt = 0; mt < 4; mt++)
            #pragma unroll
            for (int nt = 0; nt < 4; nt++)
                acc[mt][nt] = __builtin_amdgcn_mfma_i32_16x16x64_i8(a[mt], bb[nt], acc[mt][nt], 0,0,0);
    }
}

// attn as int8 MFMA GEMM + fused epilogue chain
__global__ __launch_bounds__(256) void k_attn(const char* __restrict__ ws,
                                              const float* __restrict__ x,
                                              const float* __restrict__ act){
    __shared__ char smem[32768];
    const float* fws = (const float*)ws;
    const int*   iws = (const int*)ws;
    const i8* A  = (const i8*)(ws + OFF_WA);
    const i8* Bq = (const i8*)(ws + OFF_Q1T) + (size_t)blockIdx.z*768*NP;
    i8* x2 = (i8*)(ws + OFF_X2);
    i8* q3 = (i8*)(ws + OFF_Q3);
    int b = blockIdx.z;
    int m0 = blockIdx.x*128, n0 = blockIdx.y*128;
    int t = threadIdx.x, lane = t & 63;
    int wm = (t>>6)&1, wn = t>>7;
    int4v acc[4][4]; int4v zz = {0,0,0,0};
    #pragma unroll
    for (int mt=0;mt<4;mt++) for (int nt=0;nt<4;nt++) acc[mt][nt] = zz;
    gemm_i8_loop(A, Bq, NP, NP, m0, n0, NP, acc, (i8*)smem, (i8*)smem+8192, t);

    float a0=act[0], a1=act[1], a2=act[2], a3=act[3], a4=act[4];
    float wasf = fws[WS_MAX+1]/127.0f; float r2  = (a1*wasf)/a2;
    float g1sf = fws[WS_MAX+2]/127.0f; float r3a = (a2*g1sf)/a3; float r3b = a0/a3;
    float w2sf = fws[WS_MAX+3]/127.0f; float r4  = (a3*w2sf)/a4;
    float g1v[4], w2v[4], b2v[4];
    #pragma unroll
    for (int nt=0;nt<4;nt++){
        int d = n0 + wn*64 + nt*16 + (lane&15);
        g1v[nt] = fws[WS_G1F + d]; w2v[nt] = fws[WS_W2F + d]; b2v[nt] = fws[WS_B2F + d];
    }
    __syncthreads();
    i8* Xs = (i8*)smem;
    i8* Qs = (i8*)smem + 16384;
    #pragma unroll
    for (int mt=0;mt<4;mt++){
        #pragma unroll
        for (int r=0;r<4;r++){
            int ml = wm*64 + mt*16 + (lane>>4)*4 + r;
            int o  = m0 + ml;
            int ba = iws[WS_BA + o];
            #pragma unroll
            for (int nt=0;nt<4;nt++){
                int nl = wn*64 + nt*16 + (lane&15);
                int d  = n0 + nl;
                float s2 = (float)(acc[mt][nt][r] + ba);
                float q2 = clamp8(rintf(s2*r2));
                float o3v = q2*g1v[nt];
                float xv = (o < 196) ? x[((size_t)b*196 + o)*768 + d] : 0.f;
                float idi = rintf(xv/a0);
                float tt = rintf(o3v*r3a) + rintf(idi*r3b);
                tt = clamp8(tt);
                float o4 = tt*w2v[nt] + b2v[nt];
                float qr = clamp8(rintf(o4*r4));
                Xs[ml*128 + nl] = (i8)(int)tt;
                Qs[ml*128 + nl] = (i8)(int)qr;
            }
        }
    }
    __syncthreads();
    #pragma unroll
    for (int e=0;e<4;e++){
        int id = t + e*256;
        int row = id>>3, c = id&7;
        int o = m0 + row;
        if (o < 196){
            size_t g = ((size_t)b*196 + o)*768 + n0 + c*16;
            *(int4v*)(x2 + g) = *(const int4v*)(Xs + row*128 + c*16);
            *(int4v*)(q3 + g) = *(const int4v*)(Qs + row*128 + c*16);
        }
    }
}

// fc1: q3[12544,768] x fc1_int[3072,768]^T -> relu -> quant -> q4 int8
__global__ __launch_bounds__(256) void k_fc1(const char* __restrict__ ws, const float* __restrict__ act){
    __shared__ char smem[16384];
    const float* fws = (const float*)ws;
    const int*   iws = (const int*)ws;
    const i8* qa = (const i8*)(ws+OFF_Q3);
    const i8* wb = (const i8*)(ws+OFF_FC1);
    const int* bias = iws + WS_BF1;
    i8* qout = (i8*)(ws+OFF_Q4);
    int m0 = blockIdx.x*128, n0 = blockIdx.y*128;
    int t = threadIdx.x, lane = t & 63;
    int wm = (t>>6)&1, wn = t>>7;
    int4v acc[4][4]; int4v zz = {0,0,0,0};
    #pragma unroll
    for (int mt=0;mt<4;mt++) for (int nt=0;nt<4;nt++) acc[mt][nt] = zz;
    gemm_i8_loop(qa, wb, 768, 768, m0, n0, 768, acc, (i8*)smem, (i8*)smem+8192, t);
    float wsf = fws[WS_MAX+4]/127.0f;
    float r5 = (act[4]*wsf)/act[5];
    int bcol[4];
    #pragma unroll
    for (int nt=0;nt<4;nt++) bcol[nt] = bias[n0 + wn*64 + nt*16 + (lane&15)];
    __syncthreads();
    i8* Cs = (i8*)smem;
    #pragma unroll
    for (int mt=0;mt<4;mt++){
        #pragma unroll
        for (int nt=0;nt<4;nt++){
            int nl = wn*64 + nt*16 + (lane&15);
            #pragma unroll
            for (int r=0;r<4;r++){
                int s = acc[mt][nt][r] + bcol[nt];
                if (s < 0) s = 0;
                float q = clamp8(rintf((float)s * r5));
                int ml = wm*64 + mt*16 + (lane>>4)*4 + r;
                Cs[ml*128 + nl] = (i8)(int)q;
            }
        }
    }
    __syncthreads();
    #pragma unroll
    for (int e=0;e<4;e++){
        int id2 = t + e*256;
        int row = id2>>3, c = id2&7;
        *(int4v*)(qout + (size_t)(m0+row)*3072 + n0 + c*16) = *(const int4v*)(Cs + row*128 + c*16);
    }
}

// fc2: q4[12544,3072] x fc2_int[768,3072]^T -> quant -> gamma2 -> +identity -> final quant -> fp32
__global__ __launch_bounds__(256) void k_fc2(const char* __restrict__ ws, const float* __restrict__ act,
                                             float* __restrict__ out){
    __shared__ char smem[16384];
    const float* fws = (const float*)ws;
    const int*   iws = (const int*)ws;
    const i8* qa = (const i8*)(ws+OFF_Q4);
    const i8* wb = (const i8*)(ws+OFF_FC2);
    const int* bias = iws + WS_BF2;
    const float* g2f = fws + WS_G2F;
    const i8* x2 = (const i8*)(ws+OFF_X2);
    int m0 = blockIdx.x*128, n0 = blockIdx.y*128;
    int t = threadIdx.x, lane = t & 63;
    int wm = (t>>6)&1, wn = t>>7;
    int4v acc[4][4]; int4v zz = {0,0,0,0};
    #pragma unroll
    for (int mt=0;mt<4;mt++) for (int nt=0;nt<4;nt++) acc[mt][nt] = zz;
    gemm_i8_loop(qa, wb, 3072, 3072, m0, n0, 3072, acc, (i8*)smem, (i8*)smem+8192, t);
    float a3=act[3], a5=act[5], a6=act[6], a7=act[7];
    float wsf  = fws[WS_MAX+5]/127.0f; float r6  = (a5*wsf)/a6;
    float g2sf = fws[WS_MAX+6]/127.0f; float r7a = (a6*g2sf)/a7; float r7b = a3/a7;
    int bcol[4]; float g2v[4];
    #pragma unroll
    for (int nt=0;nt<4;nt++){
        int nc = n0 + wn*64 + nt*16 + (lane&15);
        bcol[nt] = bias[nc]; g2v[nt] = g2f[nc];
    }
    #pragma unroll
    for (int mt=0;mt<4;mt++){
        #pragma unroll
        for (int nt=0;nt<4;nt++){
            int nc = n0 + wn*64 + nt*16 + (lane&15);
            #pragma unroll
            for (int r=0;r<4;r++){
                int ml = wm*64 + mt*16 + (lane>>4)*4 + r;
                size_t gi = (size_t)(m0+ml)*768 + nc;
                int s = acc[mt][nt][r] + bcol[nt];
                float q6 = clamp8(rintf((float)s*r6));
                float o7 = q6*g2v[nt];
                float idi = (float)x2[gi];
                float tt = rintf(o7*r7a) + rintf(idi*r7b);
                tt = clamp8(tt);
                out[gi] = tt*a7;
            }
        }
    }
}

extern "C" void kernel_launch(void* const* d_in, const int* in_sizes, int n_in,
                              void* d_out, int out_size, void* d_ws, size_t ws_size,
                              hipStream_t stream){
    const float* x   = (const float*)d_in[0];
    const float* n1w = (const float*)d_in[1];
    const float* n1b = (const float*)d_in[2];
    const float* aw  = (const float*)d_in[3];
    const float* ab  = (const float*)d_in[4];
    const float* g1w = (const float*)d_in[5];
    const float* n2w = (const float*)d_in[6];
    const float* n2b = (const float*)d_in[7];
    const float* f1w = (const float*)d_in[8];
    const float* f1b = (const float*)d_in[9];
    const float* f2w = (const float*)d_in[10];
    const float* f2b = (const float*)d_in[11];
    const float* g2w = (const float*)d_in[12];
    const float* act = (const float*)d_in[13];
    char* ws = (char*)d_ws;
    float* out = (float*)d_out;

    k_init<<<16,256,0,stream>>>(ws, act, out + (size_t)B_*N_*D_);
    k_maxabs<<<dim3(120,7),256,0,stream>>>(n1w, aw, g1w, n2w, f1w, f2w, g2w, (float*)ws);
    long qwThreads = 2L*589824 + 38416 + 768L*6 + 196 + 3072 + 768;
    k_qweights<<<(int)((qwThreads+255)/256),256,0,stream>>>(n1w,n1b,aw,ab,g1w,n2w,n2b,
                                                            f1w,f1b,f2w,f2b,g2w,act,ws);
    k_stage1<<<dim3(12,4,64),256,0,stream>>>(x, ws, ws, act);
    k_attn<<<dim3(2,6,64),256,0,stream>>>(ws, x, act);
    k_fc1<<<dim3(98,24),256,0,stream>>>(ws, act);
    k_fc2<<<dim3(98,6),256,0,stream>>>(ws, act, out);
}